// Round 1
// baseline (225.775 us; speedup 1.0000x reference)
//
#include <hip/hip_runtime.h>

typedef float  f32x4  __attribute__((ext_vector_type(4)));
typedef __bf16 bf16x8 __attribute__((ext_vector_type(8)));

#define LDS_AS(p)  ((__attribute__((address_space(3))) void*)(p))
#define GLB_AS(p)  ((const __attribute__((address_space(1))) void*)(p))

__device__ __forceinline__ unsigned short f2bf(float f){
  unsigned u = __float_as_uint(f);
  return (unsigned short)((u + 0x7fffu + ((u >> 16) & 1u)) >> 16);  // RNE
}

// ---------------- prep: fuse Wk|Wv -> Wt bf16 [1024 fused cols][512 d], zero acc
// fused col f: group gf=f>>4 ; gf even = K-chunk, odd = V-chunk ; src col c=(gf>>1)*16+(f&15)
__global__ void prep_kernel(const float* __restrict__ Wk, const float* __restrict__ Wv,
                            unsigned short* __restrict__ Wt, float* __restrict__ accg){
  int i = blockIdx.x * 256 + threadIdx.x;          // 0..524287
  if (i < 4096) accg[i] = 0.f;                     // [4][1024]: KV | Ksum
  int f  = i >> 9, d = i & 511;
  int gf = f >> 4, t = f & 15;
  int c  = (gf >> 1) * 16 + t;                     // col in [0,512), == h*64+hd
  const float* W = (gf & 1) ? Wv : Wk;
  int h = c >> 6, hd = c & 63;
  Wt[i] = f2bf(W[(h * 512 + d) * 64 + hd]);
}

// ---------------- main: C = x @ Wt (bf16 MFMA), reduce K*V and K over rows -> atomics
__global__ __launch_bounds__(256) void kv_kernel(const float* __restrict__ x,
    const unsigned short* __restrict__ Wt, const float* __restrict__ bk,
    const float* __restrict__ bv, float* __restrict__ accg){
  __shared__ float          As[128 * 32];          // fp32 x tile, XOR-swizzled
  __shared__ unsigned short Bs[128 * 32];          // bf16 W tile (col-major), XOR-swizzled

  int bid = blockIdx.x;
  int wg  = (bid & 7) * 256 + (bid >> 3);          // XCD swizzle (2048 % 8 == 0)
  int panel = wg >> 3;                             // 0..255 row panels (64 per n)
  int bcol  = wg & 7;                              // 0..7 col tiles of 128
  int row0  = panel << 7;
  int n     = panel >> 6;
  int tid = threadIdx.x;
  int l = tid & 63, w = tid >> 6;
  int wr = w >> 1, wc = w & 1;

  const f32x4 vz = {0.f, 0.f, 0.f, 0.f};
  f32x4 accv[4][4];
  #pragma unroll
  for (int m = 0; m < 4; ++m)
    #pragma unroll
    for (int q = 0; q < 4; ++q) accv[m][q] = vz;

  for (int kt = 0; kt < 16; ++kt){
    if (kt) __syncthreads();
    // stage A: 16 KB, 4 x 1KB insts per wave; linear LDS dest, inverse-swizzled source
    #pragma unroll
    for (int i = 0; i < 4; ++i){
      int L   = (w * 4 + i) * 1024 + l * 16;
      int row = L >> 7;
      int s   = L & 127;
      int sb  = kt * 128 + (s ^ ((row & 7) << 4));
      const char* g = (const char*)x + (size_t)(row0 + row) * 2048 + sb;
      char* lb = (char*)As + (size_t)(w * 4 + i) * 1024;   // wave-uniform base
      __builtin_amdgcn_global_load_lds(GLB_AS(g), LDS_AS(lb), 16, 0, 0);
    }
    // stage B: 8 KB, 2 x 1KB insts per wave
    #pragma unroll
    for (int i = 0; i < 2; ++i){
      int L   = (w * 2 + i) * 1024 + l * 16;
      int col = L >> 6;
      int s   = L & 63;
      int sb  = kt * 64 + (s ^ ((col & 3) << 4));
      const char* g = (const char*)Wt + (size_t)(bcol * 128 + col) * 1024 + sb;
      char* lb = (char*)Bs + (size_t)(w * 2 + i) * 1024;
      __builtin_amdgcn_global_load_lds(GLB_AS(g), LDS_AS(lb), 16, 0, 0);
    }
    __syncthreads();                                // drains vmcnt before barrier

    bf16x8 aF[4], bF[4];
    #pragma unroll
    for (int m = 0; m < 4; ++m){
      int row = wr * 64 + m * 16 + (l & 15);
      int kb  = (l >> 4) * 32;
      int sw  = (row & 7) << 4;
      const char* base = (const char*)As + row * 128;
      float4 f0 = *(const float4*)(base + ((kb     ) ^ sw));
      float4 f1 = *(const float4*)(base + ((kb + 16) ^ sw));
      bf16x8 v;
      v[0]=(__bf16)f0.x; v[1]=(__bf16)f0.y; v[2]=(__bf16)f0.z; v[3]=(__bf16)f0.w;
      v[4]=(__bf16)f1.x; v[5]=(__bf16)f1.y; v[6]=(__bf16)f1.z; v[7]=(__bf16)f1.w;
      aF[m] = v;
    }
    #pragma unroll
    for (int q = 0; q < 4; ++q){
      int col = wc * 64 + q * 16 + (l & 15);
      int kb  = (l >> 4) * 16;
      bF[q] = *(const bf16x8*)((const char*)Bs + col * 64 + (kb ^ ((col & 3) << 4)));
    }
    #pragma unroll
    for (int m = 0; m < 4; ++m)
      #pragma unroll
      for (int q = 0; q < 4; ++q)
        accv[m][q] = __builtin_amdgcn_mfma_f32_16x16x32_bf16(aF[m], bF[q], accv[m][q], 0, 0, 0);
  }

  // epilogue: frag pairs (q, q+1) = (K cols, V cols) at identical (row, src col)
  #pragma unroll
  for (int p = 0; p < 2; ++p){
    int q = p * 2;
    int c = (bcol * 4 + wc * 2 + p) * 16 + (l & 15);   // source col in [0,512)
    float bkc = bk[c], bvc = bv[c];
    float sKV = 0.f, sK = 0.f;
    #pragma unroll
    for (int m = 0; m < 4; ++m)
      #pragma unroll
      for (int r = 0; r < 4; ++r){
        float kp  = accv[m][q][r] + bkc;
        float kvv = kp > 0.f ? kp + 1.f : __expf(kp);  // elu(x)+1
        sKV += kvv * (accv[m][q + 1][r] + bvc);
        sK  += kvv;
      }
    sKV += __shfl_xor(sKV, 16); sKV += __shfl_xor(sKV, 32);
    sK  += __shfl_xor(sK , 16); sK  += __shfl_xor(sK , 32);
    if ((l >> 4) == 0){
      atomicAdd(&accg[n * 1024 + c],       sKV);
      atomicAdd(&accg[n * 1024 + 512 + c], sK);
    }
  }
}

// ---------------- finalize: O = KV/Ksum ; out_row = gelu_tanh(O @ Wo + bo)
__global__ void finalize_kernel(const float* __restrict__ accg, const float* __restrict__ Wo,
                                const float* __restrict__ bo, float* __restrict__ rows){
  __shared__ float Ov[512];
  int n = blockIdx.x, o = threadIdx.x;
  Ov[o] = accg[n * 1024 + o] / accg[n * 1024 + 512 + o];
  __syncthreads();
  float s = bo[o];
  #pragma unroll 8
  for (int c = 0; c < 512; ++c) s += Ov[c] * Wo[c * 512 + o];
  float t = 0.7978845608028654f * (s + 0.044715f * s * s * s);
  rows[n * 512 + o] = 0.5f * s * (1.f + tanhf(t));
}

// ---------------- broadcast: out[n,s,:] = rows[n,:]
__global__ void bcast_kernel(const float* __restrict__ rows, float4* __restrict__ out){
  int i = blockIdx.x * 256 + threadIdx.x;            // 0..4194303 float4s
  int n  = i >> 20;                                  // 8192*512/4 = 2^20 per n
  int o4 = i & 127;
  out[i] = *(const float4*)(rows + n * 512 + o4 * 4);
}

extern "C" void kernel_launch(void* const* d_in, const int* in_sizes, int n_in,
                              void* d_out, int out_size, void* d_ws, size_t ws_size,
                              hipStream_t stream){
  const float* x  = (const float*)d_in[0];
  // d_in[1]=Wq, d_in[2]=bq  — provably irrelevant (eps/(Q*Ksum) ~ 3e-8 relative)
  const float* Wk = (const float*)d_in[3];
  const float* bk = (const float*)d_in[4];
  const float* Wv = (const float*)d_in[5];
  const float* bv = (const float*)d_in[6];
  const float* Wo = (const float*)d_in[7];
  const float* bo = (const float*)d_in[8];
  float* out = (float*)d_out;

  char* ws = (char*)d_ws;
  unsigned short* Wt = (unsigned short*)ws;            // 1 MB  bf16 [1024][512]
  float* accg = (float*)(ws + (1 << 20));              // 16 KB [4][1024]
  float* rows = (float*)(ws + (1 << 20) + 16384);      // 8 KB  [4][512]

  prep_kernel    <<<2048, 256, 0, stream>>>(Wk, Wv, Wt, accg);
  kv_kernel      <<<2048, 256, 0, stream>>>(x, Wt, bk, bv, accg);
  finalize_kernel<<<4, 512, 0, stream>>>(accg, Wo, bo, rows);
  bcast_kernel   <<<16384, 256, 0, stream>>>(rows, (float4*)out);
}

// Round 2
// 178.693 us; speedup vs baseline: 1.2635x; 1.2635x over previous
//
#include <hip/hip_runtime.h>

typedef __bf16 bf16x8 __attribute__((ext_vector_type(8)));
typedef float  f32x4  __attribute__((ext_vector_type(4)));

#define LDS_AS(p)  ((__attribute__((address_space(3))) void*)(p))
#define GLB_AS(p)  ((const __attribute__((address_space(1))) void*)(p))

__device__ __forceinline__ unsigned short f2bf(float f){
  unsigned u = __float_as_uint(f);
  return (unsigned short)((u + 0x7fffu + ((u >> 16) & 1u)) >> 16);  // RNE
}

// ---------------- prep: fuse Wk|Wv -> Wt bf16 [1024 fused cols][512 d], zero accumulators
// fused col f: group gf=f>>4 ; gf even = K-chunk, odd = V-chunk ; src col c=(gf>>1)*16+(f&15)
__global__ void prep_kernel(const float* __restrict__ Wk, const float* __restrict__ Wv,
                            unsigned short* __restrict__ Wt, float* __restrict__ accg){
  int i = blockIdx.x * 256 + threadIdx.x;          // 0..524287
  if (i < 6144) accg[i] = 0.f;                     // accg[4][1024] (KV|Ksum) + pre[4][512]
  int f  = i >> 9, d = i & 511;
  int gf = f >> 4, t = f & 15;
  int c  = (gf >> 1) * 16 + t;                     // col in [0,512) == h*64+hd
  const float* W = (gf & 1) ? Wv : Wk;
  int h = c >> 6, hd = c & 63;
  Wt[i] = f2bf(W[(h * 512 + d) * 64 + hd]);
}

// ---------------- main: C = x @ Wt (bf16 MFMA), reduce K*V and K over rows -> atomics
// 128x128 tile, BK=64, 4 waves (2x2). A reg-staged fp32->bf16; B via global_load_lds.
// LDS rows are 128 B = 8 x 16B slots; swizzle: byte ^= ((row>>1)&7)<<4 (bijective, conflict-free
// for 16-lane frag reads; matching inverse-swizzle on B's global source address).
__global__ __launch_bounds__(256) void kv_kernel(const float* __restrict__ x,
    const unsigned short* __restrict__ Wt, const float* __restrict__ bk,
    const float* __restrict__ bv, float* __restrict__ accg){
  __shared__ __align__(16) unsigned short As[128 * 64];  // bf16 x tile   16 KB
  __shared__ __align__(16) unsigned short Bs[128 * 64];  // bf16 W tile   16 KB

  int bid = blockIdx.x;
  int wg  = (bid & 7) * 256 + (bid >> 3);          // XCD swizzle (2048 % 8 == 0)
  int panel = wg >> 3;                             // 0..255 row panels (64 per n)
  int bcol  = wg & 7;                              // 0..7 col tiles of 128
  int row0  = panel << 7;
  int n     = panel >> 6;
  int tid = threadIdx.x;
  int l = tid & 63, w = tid >> 6;
  int wr = w >> 1, wc = w & 1;

  const f32x4 vz = {0.f, 0.f, 0.f, 0.f};
  f32x4 accv[4][4];
  #pragma unroll
  for (int m = 0; m < 4; ++m)
    #pragma unroll
    for (int q = 0; q < 4; ++q) accv[m][q] = vz;

  // A staging geometry: lane covers row rj = w*32+(l>>3)+8j (j=0..3), 32B fp32 chunk cc=l&7
  int rA = w * 32 + (l >> 3);
  int cc = l & 7;
  const float* xg = x + (size_t)(row0 + rA) * 512 + cc * 8;   // + kt*64 + j*8*512

  float4 fA[4][2];
  #pragma unroll
  for (int j = 0; j < 4; ++j){                     // prologue: kt=0 A loads
    const float* g = xg + (size_t)j * 8 * 512;
    fA[j][0] = *(const float4*)g;
    fA[j][1] = *(const float4*)(g + 4);
  }

  for (int kt = 0; kt < 8; ++kt){
    if (kt) __syncthreads();                       // prev-iter LDS reads done
    // ---- stage A: cvt + swizzled ds_write_b128
    #pragma unroll
    for (int j = 0; j < 4; ++j){
      int r  = rA + 8 * j;
      int sw = ((r >> 1) & 7) << 4;
      float4 f0 = fA[j][0], f1 = fA[j][1];
      bf16x8 v;
      v[0]=(__bf16)f0.x; v[1]=(__bf16)f0.y; v[2]=(__bf16)f0.z; v[3]=(__bf16)f0.w;
      v[4]=(__bf16)f1.x; v[5]=(__bf16)f1.y; v[6]=(__bf16)f1.z; v[7]=(__bf16)f1.w;
      *(bf16x8*)((char*)As + r * 128 + ((cc * 16) ^ sw)) = v;
    }
    // ---- stage B: 16 KB via global_load_lds, linear dest, inverse-swizzled source
    #pragma unroll
    for (int i = 0; i < 4; ++i){
      int L   = (w * 4 + i) * 1024 + l * 16;
      int col = L >> 7;
      int s   = L & 127;
      int sb  = kt * 128 + (s ^ (((col >> 1) & 7) << 4));
      const char* g = (const char*)Wt + (size_t)(bcol * 128 + col) * 1024 + sb;
      char* lb = (char*)Bs + (size_t)(w * 4 + i) * 1024;   // wave-uniform base
      __builtin_amdgcn_global_load_lds(GLB_AS(g), LDS_AS(lb), 16, 0, 0);
    }
    __syncthreads();                               // drains B loads + A writes

    if (kt < 7){                                   // prefetch next A tile -> regs
      const float* gk = xg + (kt + 1) * 64;        // hides under MFMA phase
      #pragma unroll
      for (int j = 0; j < 4; ++j){
        const float* g = gk + (size_t)j * 8 * 512;
        fA[j][0] = *(const float4*)g;
        fA[j][1] = *(const float4*)(g + 4);
      }
    }

    // ---- compute: 2 x (8 ds_read_b128 + 16 MFMA)
    #pragma unroll
    for (int kk = 0; kk < 2; ++kk){
      bf16x8 aF[4], bF[4];
      int kb = kk * 64 + (l >> 4) * 16;
      #pragma unroll
      for (int m = 0; m < 4; ++m){
        int row = wr * 64 + m * 16 + (l & 15);
        aF[m] = *(const bf16x8*)((const char*)As + row * 128 + (kb ^ (((row >> 1) & 7) << 4)));
      }
      #pragma unroll
      for (int q = 0; q < 4; ++q){
        int col = wc * 64 + q * 16 + (l & 15);
        bF[q] = *(const bf16x8*)((const char*)Bs + col * 128 + (kb ^ (((col >> 1) & 7) << 4)));
      }
      #pragma unroll
      for (int m = 0; m < 4; ++m)
        #pragma unroll
        for (int q = 0; q < 4; ++q)
          accv[m][q] = __builtin_amdgcn_mfma_f32_16x16x32_bf16(aF[m], bF[q], accv[m][q], 0, 0, 0);
    }
  }

  // epilogue: frag pairs (q, q+1) = (K cols, V cols) at identical (row, src col)
  #pragma unroll
  for (int p = 0; p < 2; ++p){
    int q = p * 2;
    int c = (bcol * 4 + wc * 2 + p) * 16 + (l & 15);   // source col in [0,512)
    float bkc = bk[c], bvc = bv[c];
    float sKV = 0.f, sK = 0.f;
    #pragma unroll
    for (int m = 0; m < 4; ++m)
      #pragma unroll
      for (int r = 0; r < 4; ++r){
        float kp  = accv[m][q][r] + bkc;
        float kvv = kp > 0.f ? kp + 1.f : __expf(kp);  // elu(x)+1
        sKV += kvv * (accv[m][q + 1][r] + bvc);
        sK  += kvv;
      }
    sKV += __shfl_xor(sKV, 16); sKV += __shfl_xor(sKV, 32);
    sK  += __shfl_xor(sK , 16); sK  += __shfl_xor(sK , 32);
    if ((l >> 4) == 0){
      atomicAdd(&accg[n * 1024 + c],       sKV);
      atomicAdd(&accg[n * 1024 + 512 + c], sK);
    }
  }
}

// ---------------- finalize1: pre[n,o] += sum_{c in 8-chunk} (KV/Ksum)[c] * Wo[c,o]
__global__ void fin1_kernel(const float* __restrict__ accg, const float* __restrict__ Wo,
                            float* __restrict__ pre){
  int b = blockIdx.x;                              // 256 = 4 n * 64 c-chunks
  int n = b >> 6, cb = b & 63;
  int t = threadIdx.x;
  __shared__ float ov[8];
  if (t < 8){ int c = cb * 8 + t; ov[t] = accg[n * 1024 + c] / accg[n * 1024 + 512 + c]; }
  __syncthreads();
  float s0 = 0.f, s1 = 0.f;
  #pragma unroll
  for (int j = 0; j < 8; ++j){
    int c = cb * 8 + j;
    s0 += ov[j] * Wo[c * 512 + t];
    s1 += ov[j] * Wo[c * 512 + 256 + t];
  }
  atomicAdd(&pre[n * 512 + t],       s0);
  atomicAdd(&pre[n * 512 + 256 + t], s1);
}

// ---------------- finalize2: rows = gelu_tanh(pre + bo)
__global__ void fin2_kernel(const float* __restrict__ pre, const float* __restrict__ bo,
                            float* __restrict__ rows){
  int i = blockIdx.x * 512 + threadIdx.x;          // 2048
  float s = pre[i] + bo[i & 511];
  float t = 0.7978845608028654f * (s + 0.044715f * s * s * s);
  rows[i] = 0.5f * s * (1.f + tanhf(t));
}

// ---------------- broadcast: out[n,s,:] = rows[n,:]
__global__ void bcast_kernel(const float* __restrict__ rows, float4* __restrict__ out){
  int i = blockIdx.x * 256 + threadIdx.x;          // 0..4194303 float4s
  int n  = i >> 20;                                // 8192*512/4 = 2^20 per n
  int o4 = i & 127;
  out[i] = *(const float4*)(rows + n * 512 + o4 * 4);
}

extern "C" void kernel_launch(void* const* d_in, const int* in_sizes, int n_in,
                              void* d_out, int out_size, void* d_ws, size_t ws_size,
                              hipStream_t stream){
  const float* x  = (const float*)d_in[0];
  // d_in[1]=Wq, d_in[2]=bq  — provably irrelevant (eps/(Q*Ksum) ~ 3e-8 relative)
  const float* Wk = (const float*)d_in[3];
  const float* bk = (const float*)d_in[4];
  const float* Wv = (const float*)d_in[5];
  const float* bv = (const float*)d_in[6];
  const float* Wo = (const float*)d_in[7];
  const float* bo = (const float*)d_in[8];
  float* out = (float*)d_out;

  char* ws = (char*)d_ws;
  unsigned short* Wt = (unsigned short*)ws;            // 1 MB  bf16 [1024][512]
  float* accg = (float*)(ws + (1 << 20));              // 16 KB [4][1024] KV|Ksum
  float* pre  = (float*)(ws + (1 << 20) + 16384);      // 8 KB  [4][512] pre-gelu
  float* rows = (float*)(ws + (1 << 20) + 24576);      // 8 KB  [4][512] post-gelu

  prep_kernel<<<2048, 256, 0, stream>>>(Wk, Wv, Wt, accg);
  kv_kernel  <<<2048, 256, 0, stream>>>(x, Wt, bk, bv, accg);
  fin1_kernel<<<256, 256, 0, stream>>>(accg, Wo, pre);
  fin2_kernel<<<4, 512, 0, stream>>>(pre, bo, rows);
  bcast_kernel<<<16384, 256, 0, stream>>>(rows, (float4*)out);
}